// Round 3
// baseline (615.578 us; speedup 1.0000x reference)
//
#include <hip/hip_runtime.h>
#include <hip/hip_bf16.h>

typedef __hip_bfloat16 bf16;
typedef __attribute__((ext_vector_type(8))) short short8;
typedef __attribute__((ext_vector_type(4))) float f32x4;

struct alignas(8) bh4 { bf16 x, y, z, w; };

static __device__ __forceinline__ float b2f(bf16 h) { return __bfloat162float(h); }

// fast tanh: 1 - 2/(exp(2v)+1); saturates correctly via inf/0
static __device__ __forceinline__ float fast_tanh(float v) {
  float e = __expf(2.0f * v);
  return 1.0f - 2.0f * __builtin_amdgcn_rcpf(e + 1.0f);
}

// ---------------- fp32 -> bf16 conversion (x input) ------------------------
__global__ __launch_bounds__(256) void f2b_kernel(const float* __restrict__ s,
                                                  bf16* __restrict__ d, long n) {
  long i = ((long)blockIdx.x * 256 + threadIdx.x) * 4;
  if (i >= n) return;
  float4 v = *(const float4*)(s + i);
  bh4 o;
  o.x = __float2bfloat16(v.x); o.y = __float2bfloat16(v.y);
  o.z = __float2bfloat16(v.z); o.w = __float2bfloat16(v.w);
  *(bh4*)(d + i) = o;
}

// 4 x [1024,1024] fp32->bf16 in one launch
struct Ptrs4 { const float* s[4]; bf16* d[4]; };
__global__ __launch_bounds__(256) void f2b4_kernel(Ptrs4 p) {
  const int which = blockIdx.x >> 10;
  long i = ((long)(blockIdx.x & 1023) * 256 + threadIdx.x) * 4;
  float4 v = *(const float4*)(p.s[which] + i);
  bh4 o;
  o.x = __float2bfloat16(v.x); o.y = __float2bfloat16(v.y);
  o.z = __float2bfloat16(v.z); o.w = __float2bfloat16(v.w);
  *(bh4*)(p.d[which] + i) = o;
}

// ---------------- fp32 [1024,1024] -> transposed bf16 (2 mats) -------------
__global__ __launch_bounds__(256) void f2bT_kernel(const float* __restrict__ s0,
                                                   const float* __restrict__ s1,
                                                   bf16* __restrict__ d0,
                                                   bf16* __restrict__ d1) {
  const float* src = blockIdx.z ? s1 : s0;
  bf16* dst = blockIdx.z ? d1 : d0;
  __shared__ bf16 tile[64][68];
  const int t = threadIdx.x;
  const int tr = t >> 4;          // 0..15
  const int tc = (t & 15) * 4;    // 0..60
  const int r0 = blockIdx.y * 64, c0 = blockIdx.x * 64;
#pragma unroll
  for (int i = 0; i < 4; ++i) {
    float4 v = *(const float4*)(src + (long)(r0 + tr + i * 16) * 1024 + c0 + tc);
    tile[tr + i * 16][tc + 0] = __float2bfloat16(v.x);
    tile[tr + i * 16][tc + 1] = __float2bfloat16(v.y);
    tile[tr + i * 16][tc + 2] = __float2bfloat16(v.z);
    tile[tr + i * 16][tc + 3] = __float2bfloat16(v.w);
  }
  __syncthreads();
#pragma unroll
  for (int i = 0; i < 4; ++i) {
    const int c = tr + i * 16;
    bh4 o;
    o.x = tile[tc + 0][c]; o.y = tile[tc + 1][c];
    o.z = tile[tc + 2][c]; o.w = tile[tc + 3][c];
    *(bh4*)(dst + (long)(c0 + c) * 1024 + r0 + tc) = o;  // dst[C][R] = src[R][C]
  }
}

// ---------------- small copies / bias fold ---------------------------------
__global__ __launch_bounds__(256) void copyvec_kernel(const float* __restrict__ s,
                                                      float* __restrict__ d) {
  int i = blockIdx.x * 256 + threadIdx.x;
  d[i] = s[i];
}

// BBIG[1024+b] = dot(Wsel[e,:], bsel) + bpsel[e], b in [0,2048)
__global__ __launch_bounds__(256)
void biasdot_kernel(const float* __restrict__ Wkp, const float* __restrict__ bk,
                    const float* __restrict__ bkp, const float* __restrict__ Wqp,
                    const float* __restrict__ bq, const float* __restrict__ bqp,
                    float* __restrict__ BBIG) {
  const int b = blockIdx.x;
  const int half = b >> 10, e = b & 1023;
  const float* Wrow = (half ? Wqp : Wkp) + (long)e * 1024;
  const float* bsrc = half ? bq : bk;
  const int tid = threadIdx.x;
  float4 w = *(const float4*)(Wrow + tid * 4);
  float4 bb = *(const float4*)(bsrc + tid * 4);
  float p = w.x * bb.x + w.y * bb.y + w.z * bb.z + w.w * bb.w;
#pragma unroll
  for (int off = 32; off > 0; off >>= 1) p += __shfl_down(p, off, 64);
  __shared__ float rs[4];
  if ((tid & 63) == 0) rs[tid >> 6] = p;
  __syncthreads();
  if (tid == 0)
    BBIG[1024 + b] = rs[0] + rs[1] + rs[2] + rs[3] + (half ? bqp : bkp)[e];
}

// ---------------- bf16 GEMM (old 128^2 structure) — kept for prep only -----
#define TILE 128
#define BK 64

template <int MODE, int NXB>
__global__ __launch_bounds__(256)
void gemm_bt(const bf16* __restrict__ A, const bf16* __restrict__ W,
             const float* __restrict__ bias, void* __restrict__ Out,
             long lda, long ldc, int K,
             const float* __restrict__ resid) {
  __shared__ bf16 sA[TILE * BK];
  __shared__ bf16 sB[TILE * BK];

  const int id = blockIdx.x;
  const int xcd = id & 7;
  const int loc = id >> 3;
  const int bx = xcd * NXB + loc % NXB;
  const int by = loc / NXB;

  const int tid = threadIdx.x;
  const long row0 = (long)by * TILE;
  const long col0 = (long)bx * TILE;

  if (MODE == 0 && row0 >= 1024) W += 1024L * K;

  const int wave = tid >> 6;
  const int lane = tid & 63;
  const int wm = wave >> 1, wn = wave & 1;
  const int fr = lane & 15, quad = lane >> 4;
  const int sw = fr & 7;

  f32x4 acc[4][4];
#pragma unroll
  for (int i = 0; i < 4; ++i)
#pragma unroll
    for (int j = 0; j < 4; ++j) acc[i][j] = (f32x4)0.0f;

  const int urow = tid >> 3;
  const int gcolg = (tid & 7) ^ (urow & 7);
  const int ucol = gcolg * 8;

  for (int k0 = 0; k0 < K; k0 += BK) {
#pragma unroll
    for (int r = 0; r < 4; ++r) {
      const int rr = r * 32 + urow;
      const bf16* ga = A + (row0 + rr) * lda + k0 + ucol;
      const bf16* gb = W + (col0 + rr) * (long)K + k0 + ucol;
      bf16* la = &sA[(r * 256 + (wave << 6)) * 8];
      bf16* lb = &sB[(r * 256 + (wave << 6)) * 8];
      __builtin_amdgcn_global_load_lds((const __attribute__((address_space(1))) void*)ga,
                                       (__attribute__((address_space(3))) void*)la, 16, 0, 0);
      __builtin_amdgcn_global_load_lds((const __attribute__((address_space(1))) void*)gb,
                                       (__attribute__((address_space(3))) void*)lb, 16, 0, 0);
    }
    __syncthreads();

#pragma unroll
    for (int kk = 0; kk < BK; kk += 32) {
      const int kg = kk >> 3;
      short8 af[4], bfv[4];
#pragma unroll
      for (int i = 0; i < 4; ++i)
        af[i] = *(const short8*)&sA[(wm * 64 + i * 16 + fr) * BK + (((kg + quad) ^ sw) << 3)];
#pragma unroll
      for (int j = 0; j < 4; ++j)
        bfv[j] = *(const short8*)&sB[(wn * 64 + j * 16 + fr) * BK + (((kg + quad) ^ sw) << 3)];
#pragma unroll
      for (int i = 0; i < 4; ++i)
#pragma unroll
        for (int j = 0; j < 4; ++j)
          acc[i][j] = __builtin_amdgcn_mfma_f32_16x16x32_bf16(af[i], bfv[j], acc[i][j], 0, 0, 0);
    }
    __syncthreads();
  }

  const bool do_tanh = (MODE == 1) && (col0 >= 1024);
#pragma unroll
  for (int i = 0; i < 4; ++i) {
    const long rb = row0 + wm * 64 + i * 16 + quad * 4;
#pragma unroll
    for (int j = 0; j < 4; ++j) {
      const int col = (int)col0 + wn * 64 + j * 16 + fr;
      const float bc = (MODE == 0) ? 0.0f : bias[col];
#pragma unroll
      for (int reg = 0; reg < 4; ++reg) {
        const long r = rb + reg;
        float v = acc[i][j][reg] + bc;
        if (MODE == 0) {
          ((bf16*)Out)[r * ldc + col] = __float2bfloat16(v);
        } else if (MODE == 1) {
          if (do_tanh) v = fast_tanh(v);
          ((bf16*)Out)[r * ldc + col] = __float2bfloat16(v);
        } else {
          ((float*)Out)[r * ldc + col] = v + resid[r * ldc + col];
        }
      }
    }
  }
}

// ---------------- 256^2-tile 8-wave GEMM, read-ahead pipelined -------------
// C[M,N] = A[M,K] @ W[N,K]^T (+ epilogue). 512 threads = 8 waves (2M x 4N),
// per-wave output 128x64, BK=64, LDS = 2 x (32KB A + 32KB B) double buffer.
// 4 quadrant-phases per K-tile u (buf P = u&1):
//   q1: issue b1(u) reads(4)            | Q00 = a0*b0  (a0,b0 read last phase)
//   q2: issue a1(u) reads(8)            | Q01 = a0*b1 ; vmcnt(0) retires
//       tile u+1's stage (2 phases old) ; closing barrier publishes buf^1
//   q3: issue a0(u+1) reads(8, buf^1)   | Q10 = a1*b0
//   q4: issue b0(u+1) reads(4, buf^1) + STAGE tile u+2 -> buf (8 gloads)
//                                       | Q11 = a1*b1
// Each phase: reads/stage -> barrier -> counted lgkmcnt (drains only the
// fragments this MFMA consumes; keeps the just-issued reads pending) ->
// sched_barrier(0) -> setprio(1) 16 MFMA setprio(0) -> barrier.
// DS work for phase k+1 overlaps MFMA of phase k; staging overlaps 2 phases.
// Hazards: stage->buf(u) issues only after q3's drain+barrier (all buf(u)
// reads complete); reads of buf^1 issue only after q2's vmcnt+barrier.
#define LGKM4() asm volatile("s_waitcnt lgkmcnt(4)" ::: "memory")
#define LGKM8() asm volatile("s_waitcnt lgkmcnt(8)" ::: "memory")
#define VMC8()  asm volatile("s_waitcnt vmcnt(8)" ::: "memory")
#define VMC0()  asm volatile("s_waitcnt vmcnt(0)" ::: "memory")
#define SCHED0() __builtin_amdgcn_sched_barrier(0)
#define BARX()  do { asm volatile("" ::: "memory"); __builtin_amdgcn_s_barrier(); \
                     asm volatile("" ::: "memory"); } while (0)

#define GLD(GP, LP)                                                             \
  __builtin_amdgcn_global_load_lds((const __attribute__((address_space(1))) void*)(GP), \
                                   (__attribute__((address_space(3))) void*)(LP), 16, 0, 0)

// stage the FULL K-tile T (A 256x64 + B 256x64) into buf P: 8 gloads/thread
#define STAGE_T(T, P)                                                           \
  do {                                                                          \
    const long kk0_ = (long)(T) << 6;                                           \
    _Pragma("unroll")                                                           \
    for (int r_ = 0; r_ < 4; ++r_) {                                            \
      GLD(A + (row0 + r_ * 64 + srow) * lda + kk0_ + sgcol,                     \
          sAB + (P) * 16384 + r_ * 4096 + wave * 512);                          \
      GLD(W + (col0 + r_ * 64 + srow) * ldb + kk0_ + sgcol,                     \
          sAB + 32768 + (P) * 16384 + r_ * 4096 + wave * 512);                  \
    }                                                                           \
  } while (0)

// read A frag half IH (4 frags x 2 k-slices = 8 ds_read_b128) into DST[4][2]
#define LDA4D(DST, P, IH)                                                       \
  do {                                                                          \
    _Pragma("unroll")                                                           \
    for (int i2 = 0; i2 < 4; ++i2)                                              \
      _Pragma("unroll")                                                         \
      for (int kk = 0; kk < 2; ++kk)                                            \
        DST[i2][kk] = *(const short8*)(sAB + (P) * 16384 +                      \
            (wm * 128 + ((IH) * 4 + i2) * 16 + fr) * 64 + (((kk * 4 + quad) ^ sw) << 3)); \
  } while (0)

// read B frag half JH (2 frags x 2 k-slices = 4 ds_read_b128) into DST[2][2]
#define LDB2D(DST, P, JH)                                                       \
  do {                                                                          \
    _Pragma("unroll")                                                           \
    for (int j2 = 0; j2 < 2; ++j2)                                              \
      _Pragma("unroll")                                                         \
      for (int kk = 0; kk < 2; ++kk)                                            \
        DST[j2][kk] = *(const short8*)(sAB + 32768 + (P) * 16384 +              \
            (wn * 64 + ((JH) * 2 + j2) * 16 + fr) * 64 + (((kk * 4 + quad) ^ sw) << 3)); \
  } while (0)

// one C-quadrant: 16 MFMA (4 M-frags x 2 N-frags x 2 k-slices)
#define QX(AF, BF, MH, NH)                                                      \
  do {                                                                          \
    __builtin_amdgcn_s_setprio(1);                                              \
    _Pragma("unroll")                                                           \
    for (int kk = 0; kk < 2; ++kk)                                              \
      _Pragma("unroll")                                                         \
      for (int i2 = 0; i2 < 4; ++i2)                                            \
        _Pragma("unroll")                                                       \
        for (int j2 = 0; j2 < 2; ++j2)                                          \
          acc[(MH) * 4 + i2][(NH) * 2 + j2] = __builtin_amdgcn_mfma_f32_16x16x32_bf16( \
              AF[i2][kk], BF[j2][kk], acc[(MH) * 4 + i2][(NH) * 2 + j2], 0, 0, 0); \
    __builtin_amdgcn_s_setprio(0);                                              \
  } while (0)

// 4 phases of one K-tile. u is a uniform scalar; P is a literal 0/1.
#define TILE_BODY(u, P)                                                         \
  do {                                                                          \
    /* q1 */                                                                    \
    LDB2D(b1, P, 1);                                                            \
    BARX();                                                                     \
    LGKM4(); SCHED0();                                                          \
    QX(a0, b0, 0, 0);                                                           \
    BARX();                                                                     \
    /* q2 */                                                                    \
    LDA4D(a1, P, 1);                                                            \
    BARX();                                                                     \
    LGKM8(); SCHED0();                                                          \
    QX(a0, b1, 0, 1);                                                           \
    VMC0();   /* retire tile u+1's stage (issued 2 phases ago) */               \
    BARX();   /* publishes buf^1 for q3/q4 reads */                             \
    /* q3 */                                                                    \
    if ((u) + 1 < nt) LDA4D(a0, P ^ 1, 0);                                      \
    BARX();                                                                     \
    LGKM8(); SCHED0();                                                          \
    QX(a1, b0, 1, 0);                                                           \
    BARX();   /* all buf(P) reads drained -> q4 stage into buf(P) safe */       \
    /* q4 */                                                                    \
    if ((u) + 1 < nt) LDB2D(b0, P ^ 1, 0);                                      \
    if ((u) + 2 < nt) STAGE_T((u) + 2, P);                                      \
    BARX();                                                                     \
    SCHED0();                                                                   \
    QX(a1, b1, 1, 1);                                                           \
    BARX();                                                                     \
  } while (0)

template <int MODE>
__global__ __launch_bounds__(512, 2)
void gemm256(const bf16* __restrict__ A, const bf16* __restrict__ W,
             const float* __restrict__ bias, void* __restrict__ Out,
             long lda, long ldc, int K, const float* __restrict__ resid) {
  extern __shared__ __align__(16) char smem_raw[];
  bf16* sAB = (bf16*)smem_raw;   // [0,32768): A bufs; [32768,65536): B bufs (elems)

  const int id = blockIdx.x;
  const int xcd = id & 7;
  const int loc = id >> 3;
  const int by = xcd * 8 + (loc & 7);   // M=16384 -> 64 row tiles, 8 per XCD
  const int bx = loc >> 3;
  const long row0 = (long)by * 256;
  const long col0 = (long)bx * 256;
  const long ldb = (long)K;

  const int tid = threadIdx.x;
  const int wave = tid >> 6, lane = tid & 63;
  const int wm = wave >> 2, wn = wave & 3;
  const int fr = lane & 15, quad = lane >> 4;
  const int sw = fr & 7;
  const int srow = tid >> 3;                       // 0..63 (staging row)
  const int sgcol = ((tid & 7) ^ (srow & 7)) << 3; // pre-swizzled global col

  const int nt = K >> 6;   // 16 (even)

  f32x4 acc[8][4];
#pragma unroll
  for (int i = 0; i < 8; ++i)
#pragma unroll
    for (int j = 0; j < 4; ++j) acc[i][j] = (f32x4)0.0f;

  // single-buffered fragment registers (re-read 1+ phase after last use)
  short8 a0[4][2], a1[4][2], b0[2][2], b1[2][2];

  // prologue: tiles 0 and 1 staged; retire tile 0; pre-read its a0,b0
  STAGE_T(0, 0);
  STAGE_T(1, 1);
  VMC8();
  BARX();
  LDA4D(a0, 0, 0);
  LDB2D(b0, 0, 0);

  for (int i = 0; i < nt / 2; ++i) {
    const int u0 = 2 * i, u1 = 2 * i + 1;
    TILE_BODY(u0, 0);
    TILE_BODY(u1, 1);
  }

  const bool do_tanh = (MODE == 1) && (col0 >= 1024);
  // C/D layout: col = lane&15, row = quad*4 + reg (m89/m91 verified)
#pragma unroll
  for (int mi = 0; mi < 8; ++mi) {
    const long rbase = row0 + wm * 128 + mi * 16 + quad * 4;
#pragma unroll
    for (int nj = 0; nj < 4; ++nj) {
      const int col = (int)col0 + wn * 64 + nj * 16 + fr;
      const float bc = bias[col];
#pragma unroll
      for (int reg = 0; reg < 4; ++reg) {
        const long r = rbase + reg;
        float v = acc[mi][nj][reg] + bc;
        if (MODE == 1) {
          if (do_tanh) v = fast_tanh(v);
          ((bf16*)Out)[r * ldc + col] = __float2bfloat16(v);
        } else {
          ((float*)Out)[r * ldc + col] = v + resid[r * ldc + col];
        }
      }
    }
  }
}

// ---------------- chunk-64 cumsum + retrieve + LayerNorm -------------------
__global__ __launch_bounds__(256)
void scan_ln_kernel(const bf16* __restrict__ PHS,   // [16384,3072]: V | tanh_k | tanh_q
                    const float* __restrict__ phase_scale,
                    const float* __restrict__ ln_g,
                    const float* __restrict__ ln_b,
                    bf16* __restrict__ out) {
  __shared__ bf16 sret[32 * 1040];   // stride 1040: 2-way max in phase 2
  __shared__ float psum[32 * 4], psq[32 * 4];

  const int tid = threadIdx.x;
  const long t0 = (long)blockIdx.x * 64;
  const int d = tid * 4;
  const int wid = tid >> 6, lane = tid & 63;

  const float inv2pi = 0.15915494309189535f;
  float4 ps = *(const float4*)(phase_scale + d);
  float psr[4] = {ps.x * inv2pi, ps.y * inv2pi, ps.z * inv2pi, ps.w * inv2pi};

  float ar[4] = {0.f, 0.f, 0.f, 0.f}, ai[4] = {0.f, 0.f, 0.f, 0.f};

  const int p2s = tid >> 3;          // phase-2 token slot 0..31
  const int oct = tid & 7;           // phase-2 feature octant

  for (int h = 0; h < 2; ++h) {
    for (int sl = 0; sl < 32; ++sl) {
      const long t = t0 + h * 32 + sl;
      const bf16* row = PHS + t * 3072;
      bh4 v4  = *(const bh4*)(row + d);
      bh4 tk4 = *(const bh4*)(row + 1024 + d);
      bh4 tq4 = *(const bh4*)(row + 2048 + d);
      float vv[4] = {b2f(v4.x), b2f(v4.y), b2f(v4.z), b2f(v4.w)};
      float tk[4] = {b2f(tk4.x), b2f(tk4.y), b2f(tk4.z), b2f(tk4.w)};
      float tq[4] = {b2f(tq4.x), b2f(tq4.y), b2f(tq4.z), b2f(tq4.w)};
      float ret[4];
      float lsum = 0.f, lsq = 0.f;
#pragma unroll
      for (int j = 0; j < 4; ++j) {
        float rk = tk[j] * psr[j];   // revolutions
        float rq = tq[j] * psr[j];
        float ck = __builtin_amdgcn_cosf(rk);
        float sk = __builtin_amdgcn_sinf(rk);
        float cq = __builtin_amdgcn_cosf(rq);
        float sq = __builtin_amdgcn_sinf(rq);
        ar[j] += vv[j] * ck;
        ai[j] += vv[j] * sk;
        ret[j] = (ar[j] * cq + ai[j] * sq) * 0.03125f;  // / sqrt(1024)
        lsum += ret[j];
        lsq += ret[j] * ret[j];
      }
      bh4 o;
      o.x = __float2bfloat16(ret[0]); o.y = __float2bfloat16(ret[1]);
      o.z = __float2bfloat16(ret[2]); o.w = __float2bfloat16(ret[3]);
      *(bh4*)&sret[sl * 1040 + d] = o;
#pragma unroll
      for (int off = 32; off > 0; off >>= 1) {
        lsum += __shfl_down(lsum, off, 64);
        lsq  += __shfl_down(lsq, off, 64);
      }
      if (lane == 0) { psum[sl * 4 + wid] = lsum; psq[sl * 4 + wid] = lsq; }
    }
    __syncthreads();
    {
      const int sl = p2s;
      const long t = t0 + h * 32 + sl;
      float sum = psum[sl * 4] + psum[sl * 4 + 1] + psum[sl * 4 + 2] + psum[sl * 4 + 3];
      float sq2 = psq[sl * 4] + psq[sl * 4 + 1] + psq[sl * 4 + 2] + psq[sl * 4 + 3];
      float mu = sum * (1.0f / 1024.0f);
      float var = sq2 * (1.0f / 1024.0f) - mu * mu;
      float rstd = rsqrtf(var + 1e-5f);
#pragma unroll 4
      for (int i = 0; i < 32; ++i) {
        const int f = oct * 4 + i * 32;
        bh4 r4 = *(const bh4*)&sret[sl * 1040 + f];
        float4 g4 = *(const float4*)(ln_g + f);
        float4 b4 = *(const float4*)(ln_b + f);
        bh4 o;
        o.x = __float2bfloat16((b2f(r4.x) - mu) * rstd * g4.x + b4.x);
        o.y = __float2bfloat16((b2f(r4.y) - mu) * rstd * g4.y + b4.y);
        o.z = __float2bfloat16((b2f(r4.z) - mu) * rstd * g4.z + b4.z);
        o.w = __float2bfloat16((b2f(r4.w) - mu) * rstd * g4.w + b4.w);
        *(bh4*)(out + t * 1024 + f) = o;
      }
    }
    __syncthreads();
  }
}

// ---------------------------------------------------------------------------
extern "C" void kernel_launch(void* const* d_in, const int* in_sizes, int n_in,
                              void* d_out, int out_size, void* d_ws, size_t ws_size,
                              hipStream_t stream) {
  (void)in_sizes; (void)n_in; (void)out_size; (void)ws_size;
  const float* x   = (const float*)d_in[0];
  const float* Wk  = (const float*)d_in[1];
  const float* bk  = (const float*)d_in[2];
  const float* Wv  = (const float*)d_in[3];
  const float* bv  = (const float*)d_in[4];
  const float* Wq  = (const float*)d_in[5];
  const float* bq  = (const float*)d_in[6];
  const float* Wkp = (const float*)d_in[7];
  const float* bkp = (const float*)d_in[8];
  const float* Wqp = (const float*)d_in[9];
  const float* bqp = (const float*)d_in[10];
  const float* ps  = (const float*)d_in[11];
  const float* lng = (const float*)d_in[12];
  const float* lnb = (const float*)d_in[13];
  const float* Wo  = (const float*)d_in[14];
  const float* bo  = (const float*)d_in[15];
  float* out = (float*)d_out;

  char* ws = (char*)d_ws;
  bf16*  XB   = (bf16*)(ws);                  // [16384,1024] bf16 (x, later LN out)
  bf16*  PHS  = (bf16*)(ws + 33554432);       // [16384,3072] bf16: V | tanh_k | tanh_q
  bf16*  WBIG = (bf16*)(ws + 134217728);      // [3072,1024]: Wv | Wck | Wcq
  bf16*  WOB  = (bf16*)(ws + 140509184);      // [1024,1024]
  bf16*  WPS  = (bf16*)(ws + 142606336);      // [2048,1024]: Wkp ; Wqp (bf16)
  bf16*  WTS  = (bf16*)(ws + 146800640);      // [2048,1024]: Wk^T ; Wq^T (bf16)
  float* BBIG = (float*)(ws + 150994944);     // [3072]: bv | b'k | b'q

  // conversions / weight prep
  f2b_kernel<<<16384, 256, 0, stream>>>(x, XB, 16777216L);
  Ptrs4 p4;
  p4.s[0] = Wv;  p4.d[0] = WBIG;
  p4.s[1] = Wkp; p4.d[1] = WPS;
  p4.s[2] = Wqp; p4.d[2] = WPS + 1048576;
  p4.s[3] = Wo;  p4.d[3] = WOB;
  f2b4_kernel<<<4096, 256, 0, stream>>>(p4);
  f2bT_kernel<<<dim3(16, 16, 2), 256, 0, stream>>>(Wk, Wq, WTS, WTS + 1048576);
  copyvec_kernel<<<4, 256, 0, stream>>>(bv, BBIG);
  biasdot_kernel<<<2048, 256, 0, stream>>>(Wkp, bk, bkp, Wqp, bq, bqp, BBIG);

  // prep GEMM: [Wck;Wcq] = [Wkp;Wqp] @ [Wk^T;Wq^T]^T  (M=2048,N=1024,K=1024)
  gemm_bt<0, 1><<<128, 256, 0, stream>>>(WPS, WTS, nullptr, WBIG + 1048576,
                                         1024, 1024, 1024, nullptr);
  // main GEMM: PHS = [x@Wv^T+bv | tanh(x@Wck^T+b'k) | tanh(x@Wcq^T+b'q)]
  gemm256<1><<<768, 512, 131072, stream>>>(XB, WBIG, BBIG, PHS,
                                           1024, 3072, 1024, nullptr);
  // chunk scan + retrieve + LayerNorm -> XB (reused)
  scan_ln_kernel<<<256, 256, 0, stream>>>(PHS, ps, lng, lnb, XB);
  // final GEMM: out = x + LN @ Wo^T + bo
  gemm256<2><<<256, 512, 131072, stream>>>(XB, WOB, bo, out,
                                           1024, 1024, 1024, x);
}

// Round 4
// 416.535 us; speedup vs baseline: 1.4779x; 1.4779x over previous
//
#include <hip/hip_runtime.h>
#include <hip/hip_bf16.h>

typedef __hip_bfloat16 bf16;
typedef __attribute__((ext_vector_type(8))) short short8;
typedef __attribute__((ext_vector_type(4))) float f32x4;

struct alignas(8) bh4 { bf16 x, y, z, w; };

static __device__ __forceinline__ float b2f(bf16 h) { return __bfloat162float(h); }

// fast tanh: 1 - 2/(exp(2v)+1); saturates correctly via inf/0
static __device__ __forceinline__ float fast_tanh(float v) {
  float e = __expf(2.0f * v);
  return 1.0f - 2.0f * __builtin_amdgcn_rcpf(e + 1.0f);
}

// ---------------- fp32 -> bf16 conversion (x input) ------------------------
__global__ __launch_bounds__(256) void f2b_kernel(const float* __restrict__ s,
                                                  bf16* __restrict__ d, long n) {
  long i = ((long)blockIdx.x * 256 + threadIdx.x) * 4;
  if (i >= n) return;
  float4 v = *(const float4*)(s + i);
  bh4 o;
  o.x = __float2bfloat16(v.x); o.y = __float2bfloat16(v.y);
  o.z = __float2bfloat16(v.z); o.w = __float2bfloat16(v.w);
  *(bh4*)(d + i) = o;
}

// 4 x [1024,1024] fp32->bf16 in one launch
struct Ptrs4 { const float* s[4]; bf16* d[4]; };
__global__ __launch_bounds__(256) void f2b4_kernel(Ptrs4 p) {
  const int which = blockIdx.x >> 10;
  long i = ((long)(blockIdx.x & 1023) * 256 + threadIdx.x) * 4;
  float4 v = *(const float4*)(p.s[which] + i);
  bh4 o;
  o.x = __float2bfloat16(v.x); o.y = __float2bfloat16(v.y);
  o.z = __float2bfloat16(v.z); o.w = __float2bfloat16(v.w);
  *(bh4*)(p.d[which] + i) = o;
}

// ---------------- fp32 [1024,1024] -> transposed bf16 (2 mats) -------------
__global__ __launch_bounds__(256) void f2bT_kernel(const float* __restrict__ s0,
                                                   const float* __restrict__ s1,
                                                   bf16* __restrict__ d0,
                                                   bf16* __restrict__ d1) {
  const float* src = blockIdx.z ? s1 : s0;
  bf16* dst = blockIdx.z ? d1 : d0;
  __shared__ bf16 tile[64][68];
  const int t = threadIdx.x;
  const int tr = t >> 4;          // 0..15
  const int tc = (t & 15) * 4;    // 0..60
  const int r0 = blockIdx.y * 64, c0 = blockIdx.x * 64;
#pragma unroll
  for (int i = 0; i < 4; ++i) {
    float4 v = *(const float4*)(src + (long)(r0 + tr + i * 16) * 1024 + c0 + tc);
    tile[tr + i * 16][tc + 0] = __float2bfloat16(v.x);
    tile[tr + i * 16][tc + 1] = __float2bfloat16(v.y);
    tile[tr + i * 16][tc + 2] = __float2bfloat16(v.z);
    tile[tr + i * 16][tc + 3] = __float2bfloat16(v.w);
  }
  __syncthreads();
#pragma unroll
  for (int i = 0; i < 4; ++i) {
    const int c = tr + i * 16;
    bh4 o;
    o.x = tile[tc + 0][c]; o.y = tile[tc + 1][c];
    o.z = tile[tc + 2][c]; o.w = tile[tc + 3][c];
    *(bh4*)(dst + (long)(c0 + c) * 1024 + r0 + tc) = o;  // dst[C][R] = src[R][C]
  }
}

// ---------------- small copies / bias fold ---------------------------------
__global__ __launch_bounds__(256) void copyvec_kernel(const float* __restrict__ s,
                                                      float* __restrict__ d) {
  int i = blockIdx.x * 256 + threadIdx.x;
  d[i] = s[i];
}

// BBIG[1024+b] = dot(Wsel[e,:], bsel) + bpsel[e], b in [0,2048)
__global__ __launch_bounds__(256)
void biasdot_kernel(const float* __restrict__ Wkp, const float* __restrict__ bk,
                    const float* __restrict__ bkp, const float* __restrict__ Wqp,
                    const float* __restrict__ bq, const float* __restrict__ bqp,
                    float* __restrict__ BBIG) {
  const int b = blockIdx.x;
  const int half = b >> 10, e = b & 1023;
  const float* Wrow = (half ? Wqp : Wkp) + (long)e * 1024;
  const float* bsrc = half ? bq : bk;
  const int tid = threadIdx.x;
  float4 w = *(const float4*)(Wrow + tid * 4);
  float4 bb = *(const float4*)(bsrc + tid * 4);
  float p = w.x * bb.x + w.y * bb.y + w.z * bb.z + w.w * bb.w;
#pragma unroll
  for (int off = 32; off > 0; off >>= 1) p += __shfl_down(p, off, 64);
  __shared__ float rs[4];
  if ((tid & 63) == 0) rs[tid >> 6] = p;
  __syncthreads();
  if (tid == 0)
    BBIG[1024 + b] = rs[0] + rs[1] + rs[2] + rs[3] + (half ? bqp : bkp)[e];
}

// ---------------- bf16 GEMM (old 128^2 structure) — kept for prep only -----
#define TILE 128
#define BK 64

template <int MODE, int NXB>
__global__ __launch_bounds__(256)
void gemm_bt(const bf16* __restrict__ A, const bf16* __restrict__ W,
             const float* __restrict__ bias, void* __restrict__ Out,
             long lda, long ldc, int K,
             const float* __restrict__ resid) {
  __shared__ bf16 sA[TILE * BK];
  __shared__ bf16 sB[TILE * BK];

  const int id = blockIdx.x;
  const int xcd = id & 7;
  const int loc = id >> 3;
  const int bx = xcd * NXB + loc % NXB;
  const int by = loc / NXB;

  const int tid = threadIdx.x;
  const long row0 = (long)by * TILE;
  const long col0 = (long)bx * TILE;

  if (MODE == 0 && row0 >= 1024) W += 1024L * K;

  const int wave = tid >> 6;
  const int lane = tid & 63;
  const int wm = wave >> 1, wn = wave & 1;
  const int fr = lane & 15, quad = lane >> 4;
  const int sw = fr & 7;

  f32x4 acc[4][4];
#pragma unroll
  for (int i = 0; i < 4; ++i)
#pragma unroll
    for (int j = 0; j < 4; ++j) acc[i][j] = (f32x4)0.0f;

  const int urow = tid >> 3;
  const int gcolg = (tid & 7) ^ (urow & 7);
  const int ucol = gcolg * 8;

  for (int k0 = 0; k0 < K; k0 += BK) {
#pragma unroll
    for (int r = 0; r < 4; ++r) {
      const int rr = r * 32 + urow;
      const bf16* ga = A + (row0 + rr) * lda + k0 + ucol;
      const bf16* gb = W + (col0 + rr) * (long)K + k0 + ucol;
      bf16* la = &sA[(r * 256 + (wave << 6)) * 8];
      bf16* lb = &sB[(r * 256 + (wave << 6)) * 8];
      __builtin_amdgcn_global_load_lds((const __attribute__((address_space(1))) void*)ga,
                                       (__attribute__((address_space(3))) void*)la, 16, 0, 0);
      __builtin_amdgcn_global_load_lds((const __attribute__((address_space(1))) void*)gb,
                                       (__attribute__((address_space(3))) void*)lb, 16, 0, 0);
    }
    __syncthreads();

#pragma unroll
    for (int kk = 0; kk < BK; kk += 32) {
      const int kg = kk >> 3;
      short8 af[4], bfv[4];
#pragma unroll
      for (int i = 0; i < 4; ++i)
        af[i] = *(const short8*)&sA[(wm * 64 + i * 16 + fr) * BK + (((kg + quad) ^ sw) << 3)];
#pragma unroll
      for (int j = 0; j < 4; ++j)
        bfv[j] = *(const short8*)&sB[(wn * 64 + j * 16 + fr) * BK + (((kg + quad) ^ sw) << 3)];
#pragma unroll
      for (int i = 0; i < 4; ++i)
#pragma unroll
        for (int j = 0; j < 4; ++j)
          acc[i][j] = __builtin_amdgcn_mfma_f32_16x16x32_bf16(af[i], bfv[j], acc[i][j], 0, 0, 0);
    }
    __syncthreads();
  }

  const bool do_tanh = (MODE == 1) && (col0 >= 1024);
#pragma unroll
  for (int i = 0; i < 4; ++i) {
    const long rb = row0 + wm * 64 + i * 16 + quad * 4;
#pragma unroll
    for (int j = 0; j < 4; ++j) {
      const int col = (int)col0 + wn * 64 + j * 16 + fr;
      const float bc = (MODE == 0) ? 0.0f : bias[col];
#pragma unroll
      for (int reg = 0; reg < 4; ++reg) {
        const long r = rb + reg;
        float v = acc[i][j][reg] + bc;
        if (MODE == 0) {
          ((bf16*)Out)[r * ldc + col] = __float2bfloat16(v);
        } else if (MODE == 1) {
          if (do_tanh) v = fast_tanh(v);
          ((bf16*)Out)[r * ldc + col] = __float2bfloat16(v);
        } else {
          ((float*)Out)[r * ldc + col] = v + resid[r * ldc + col];
        }
      }
    }
  }
}

// ---------------- 256^2-tile 8-wave 8-phase GEMM (m201-faithful, v2) -------
// C[M,N] = A[M,K] @ W[N,K]^T (+ epilogue). 512 threads = 8 waves (2M x 4N),
// per-wave output 128x64, BK=64, LDS 2 x 64KB double buffer.
// Per K-tile u (buf P), 4 phases; cadence invariant under (u,P)->(u+1,P^1):
//  ph1: read A frags 0-3 (8) + B frags 0-1 (4) | stage A(u+1)h0 -> P^1 | Q00
//  ph2: read B frags 2-3 (4)                   | stage A(u+1)h1 -> P^1 | Q01
//  ph3: read A frags 4-7 (8)                   | stage B(u+2)h0 -> P   | Q10
//  ph4: (no reads)            | stage B(u+2)h1 -> P ; vmcnt(4)         | Q11
// Each phase: reads+stage -> [lgkm(8) if 12 reads] -> barrier -> lgkm(0) ->
// sched_barrier(0) -> setprio(1) 16 MFMA setprio(0) -> barrier.
// Pipeline depth: every slot staged >=3 phases before first read; vmcnt(4)
// waits only on loads >=2 phases old (>= ~1200 cyc > 900 HBM latency).
// Fragment arrays are phase-local (fa reused A03 then A47): peak ~64 frag
// VGPRs + 128 acc AGPRs -> no spill (round-3 lesson).
// Hazards (all traced): slot restage is >=1 barrier after its readers'
// lgkm(0); reads of a tile come after the vmcnt+barrier that retired it.
#define LGKM0() asm volatile("s_waitcnt lgkmcnt(0)" ::: "memory")
#define LGKM8() asm volatile("s_waitcnt lgkmcnt(8)" ::: "memory")
#define VMC4()  asm volatile("s_waitcnt vmcnt(4)" ::: "memory")
#define VMC0()  asm volatile("s_waitcnt vmcnt(0)" ::: "memory")
#define SCHED0() __builtin_amdgcn_sched_barrier(0)
#define BARX()  do { asm volatile("" ::: "memory"); __builtin_amdgcn_s_barrier(); \
                     asm volatile("" ::: "memory"); } while (0)

#define GLD(GP, LP)                                                             \
  __builtin_amdgcn_global_load_lds((const __attribute__((address_space(1))) void*)(GP), \
                                   (__attribute__((address_space(3))) void*)(LP), 16, 0, 0)

// stage A M-half H (rows H*128..H*128+127) of K-tile T into buf P (2 gloads)
#define STAGE_AH(T, P, H)                                                       \
  do {                                                                          \
    const long kk0_ = (long)(T) << 6;                                           \
    _Pragma("unroll")                                                           \
    for (int r_ = 0; r_ < 2; ++r_)                                              \
      GLD(A + (row0 + (H) * 128 + r_ * 64 + srow) * lda + kk0_ + sgcol,         \
          sAB + (P) * 16384 + (H) * 8192 + r_ * 4096 + wave * 512);             \
  } while (0)

// stage B N-half H (cols H*128..H*128+127) of K-tile T into buf P (2 gloads)
#define STAGE_BH(T, P, H)                                                       \
  do {                                                                          \
    const long kk0_ = (long)(T) << 6;                                           \
    _Pragma("unroll")                                                           \
    for (int r_ = 0; r_ < 2; ++r_)                                              \
      GLD(W + (col0 + (H) * 128 + r_ * 64 + srow) * ldb + kk0_ + sgcol,         \
          sAB + 32768 + (P) * 16384 + (H) * 8192 + r_ * 4096 + wave * 512);     \
  } while (0)

// read A frags FI0..FI0+3 (8 ds_read_b128) into DST[4][2]
#define RD_A(DST, P, FI0)                                                       \
  do {                                                                          \
    _Pragma("unroll")                                                           \
    for (int i2 = 0; i2 < 4; ++i2)                                              \
      _Pragma("unroll")                                                         \
      for (int kk = 0; kk < 2; ++kk)                                            \
        DST[i2][kk] = *(const short8*)(sAB + (P) * 16384 +                      \
            (wm * 128 + ((FI0) + i2) * 16 + fr) * 64 + (((kk * 4 + quad) ^ sw) << 3)); \
  } while (0)

// read B frags FJ0..FJ0+1 (4 ds_read_b128) into DST[2][2]
#define RD_B(DST, P, FJ0)                                                       \
  do {                                                                          \
    _Pragma("unroll")                                                           \
    for (int j2 = 0; j2 < 2; ++j2)                                              \
      _Pragma("unroll")                                                         \
      for (int kk = 0; kk < 2; ++kk)                                            \
        DST[j2][kk] = *(const short8*)(sAB + 32768 + (P) * 16384 +              \
            (wn * 64 + ((FJ0) + j2) * 16 + fr) * 64 + (((kk * 4 + quad) ^ sw) << 3)); \
  } while (0)

// one C-quadrant: 16 MFMA (4 M-frags x 2 N-frags x 2 k-slices)
#define QXN(AF, BF, MH, NH)                                                     \
  do {                                                                          \
    __builtin_amdgcn_s_setprio(1);                                              \
    _Pragma("unroll")                                                           \
    for (int kk = 0; kk < 2; ++kk)                                              \
      _Pragma("unroll")                                                         \
      for (int i2 = 0; i2 < 4; ++i2)                                            \
        _Pragma("unroll")                                                       \
        for (int j2 = 0; j2 < 2; ++j2)                                          \
          acc[(MH) * 4 + i2][(NH) * 2 + j2] = __builtin_amdgcn_mfma_f32_16x16x32_bf16( \
              AF[i2][kk], BF[j2][kk], acc[(MH) * 4 + i2][(NH) * 2 + j2], 0, 0, 0); \
    __builtin_amdgcn_s_setprio(0);                                              \
  } while (0)

// 4 phases of one K-tile u reading buf P (P literal 0/1)
#define TILEPH(u, P)                                                            \
  do {                                                                          \
    /* ph1 */                                                                   \
    RD_A(fa, P, 0);                                                             \
    RD_B(fbA, P, 0);                                                            \
    if ((u) + 1 < nt) STAGE_AH((u) + 1, (P) ^ 1, 0);                            \
    LGKM8();                                                                    \
    BARX(); LGKM0(); SCHED0();                                                  \
    QXN(fa, fbA, 0, 0);                                                         \
    BARX();                                                                     \
    /* ph2 */                                                                   \
    RD_B(fbB, P, 2);                                                            \
    if ((u) + 1 < nt) STAGE_AH((u) + 1, (P) ^ 1, 1);                            \
    BARX(); LGKM0(); SCHED0();                                                  \
    QXN(fa, fbB, 0, 1);                                                         \
    BARX();                                                                     \
    /* ph3 */                                                                   \
    RD_A(fa, P, 4);                                                             \
    if ((u) + 2 < nt) STAGE_BH((u) + 2, P, 0);                                  \
    BARX(); LGKM0(); SCHED0();                                                  \
    QXN(fa, fbA, 1, 0);                                                         \
    BARX();                                                                     \
    /* ph4 */                                                                   \
    if ((u) + 2 < nt) { STAGE_BH((u) + 2, P, 1); VMC4(); }                      \
    else { VMC0(); }                                                            \
    BARX(); SCHED0();                                                           \
    QXN(fa, fbB, 1, 1);                                                         \
    BARX();                                                                     \
  } while (0)

template <int MODE>
__global__ __launch_bounds__(512, 2)
void gemm256(const bf16* __restrict__ A, const bf16* __restrict__ W,
             const float* __restrict__ bias, void* __restrict__ Out,
             long lda, long ldc, int K, const float* __restrict__ resid) {
  extern __shared__ __align__(16) char smem_raw[];
  bf16* sAB = (bf16*)smem_raw;   // [0,32768): A bufs; [32768,65536): B bufs (elems)

  const int id = blockIdx.x;
  const int xcd = id & 7;
  const int loc = id >> 3;
  const int by = xcd * 8 + (loc & 7);   // M=16384 -> 64 row tiles, 8 per XCD
  const int bx = loc >> 3;
  const long row0 = (long)by * 256;
  const long col0 = (long)bx * 256;
  const long ldb = (long)K;

  const int tid = threadIdx.x;
  const int wave = tid >> 6, lane = tid & 63;
  const int wm = wave >> 2, wn = wave & 3;
  const int fr = lane & 15, quad = lane >> 4;
  const int sw = fr & 7;
  const int srow = tid >> 3;                       // 0..63 (staging row)
  const int sgcol = ((tid & 7) ^ (srow & 7)) << 3; // pre-swizzled global col

  const int nt = K >> 6;   // 16 (even)

  f32x4 acc[8][4];
#pragma unroll
  for (int i = 0; i < 8; ++i)
#pragma unroll
    for (int j = 0; j < 4; ++j) acc[i][j] = (f32x4)0.0f;

  // phase-local fragments: fa holds A03 (ph1-2) then A47 (ph3-4)
  short8 fa[4][2], fbA[2][2], fbB[2][2];

  // prologue: tile0 (4 halves) -> buf0, B(1) (2 halves) -> buf1 [as-if ph3',4']
  STAGE_AH(0, 0, 0);
  STAGE_AH(0, 0, 1);
  STAGE_BH(0, 0, 0);
  STAGE_BH(0, 0, 1);
  STAGE_BH(1, 1, 0);
  STAGE_BH(1, 1, 1);
  VMC4();   // retire tile0's 8 loads; B(1)'s 4 stay in flight
  BARX();

  for (int it = 0; it < nt; it += 2) {
    TILEPH(it, 0);
    TILEPH(it + 1, 1);
  }

  const bool do_tanh = (MODE == 1) && (col0 >= 1024);
  // C/D layout: col = lane&15, row = quad*4 + reg (m89/m91 verified)
#pragma unroll
  for (int mi = 0; mi < 8; ++mi) {
    const long rbase = row0 + wm * 128 + mi * 16 + quad * 4;
#pragma unroll
    for (int nj = 0; nj < 4; ++nj) {
      const int col = (int)col0 + wn * 64 + nj * 16 + fr;
      const float bc = bias[col];
#pragma unroll
      for (int reg = 0; reg < 4; ++reg) {
        const long r = rbase + reg;
        float v = acc[mi][nj][reg] + bc;
        if (MODE == 1) {
          if (do_tanh) v = fast_tanh(v);
          ((bf16*)Out)[r * ldc + col] = __float2bfloat16(v);
        } else {
          ((float*)Out)[r * ldc + col] = v + resid[r * ldc + col];
        }
      }
    }
  }
}

// ---------------- chunk-64 cumsum + retrieve + LayerNorm -------------------
__global__ __launch_bounds__(256)
void scan_ln_kernel(const bf16* __restrict__ PHS,   // [16384,3072]: V | tanh_k | tanh_q
                    const float* __restrict__ phase_scale,
                    const float* __restrict__ ln_g,
                    const float* __restrict__ ln_b,
                    bf16* __restrict__ out) {
  __shared__ bf16 sret[32 * 1040];   // stride 1040: 2-way max in phase 2
  __shared__ float psum[32 * 4], psq[32 * 4];

  const int tid = threadIdx.x;
  const long t0 = (long)blockIdx.x * 64;
  const int d = tid * 4;
  const int wid = tid >> 6, lane = tid & 63;

  const float inv2pi = 0.15915494309189535f;
  float4 ps = *(const float4*)(phase_scale + d);
  float psr[4] = {ps.x * inv2pi, ps.y * inv2pi, ps.z * inv2pi, ps.w * inv2pi};

  float ar[4] = {0.f, 0.f, 0.f, 0.f}, ai[4] = {0.f, 0.f, 0.f, 0.f};

  const int p2s = tid >> 3;          // phase-2 token slot 0..31
  const int oct = tid & 7;           // phase-2 feature octant

  for (int h = 0; h < 2; ++h) {
    for (int sl = 0; sl < 32; ++sl) {
      const long t = t0 + h * 32 + sl;
      const bf16* row = PHS + t * 3072;
      bh4 v4  = *(const bh4*)(row + d);
      bh4 tk4 = *(const bh4*)(row + 1024 + d);
      bh4 tq4 = *(const bh4*)(row + 2048 + d);
      float vv[4] = {b2f(v4.x), b2f(v4.y), b2f(v4.z), b2f(v4.w)};
      float tk[4] = {b2f(tk4.x), b2f(tk4.y), b2f(tk4.z), b2f(tk4.w)};
      float tq[4] = {b2f(tq4.x), b2f(tq4.y), b2f(tq4.z), b2f(tq4.w)};
      float ret[4];
      float lsum = 0.f, lsq = 0.f;
#pragma unroll
      for (int j = 0; j < 4; ++j) {
        float rk = tk[j] * psr[j];   // revolutions
        float rq = tq[j] * psr[j];
        float ck = __builtin_amdgcn_cosf(rk);
        float sk = __builtin_amdgcn_sinf(rk);
        float cq = __builtin_amdgcn_cosf(rq);
        float sq = __builtin_amdgcn_sinf(rq);
        ar[j] += vv[j] * ck;
        ai[j] += vv[j] * sk;
        ret[j] = (ar[j] * cq + ai[j] * sq) * 0.03125f;  // / sqrt(1024)
        lsum += ret[j];
        lsq += ret[j] * ret[j];
      }
      bh4 o;
      o.x = __float2bfloat16(ret[0]); o.y = __float2bfloat16(ret[1]);
      o.z = __float2bfloat16(ret[2]); o.w = __float2bfloat16(ret[3]);
      *(bh4*)&sret[sl * 1040 + d] = o;
#pragma unroll
      for (int off = 32; off > 0; off >>= 1) {
        lsum += __shfl_down(lsum, off, 64);
        lsq  += __shfl_down(lsq, off, 64);
      }
      if (lane == 0) { psum[sl * 4 + wid] = lsum; psq[sl * 4 + wid] = lsq; }
    }
    __syncthreads();
    {
      const int sl = p2s;
      const long t = t0 + h * 32 + sl;
      float sum = psum[sl * 4] + psum[sl * 4 + 1] + psum[sl * 4 + 2] + psum[sl * 4 + 3];
      float sq2 = psq[sl * 4] + psq[sl * 4 + 1] + psq[sl * 4 + 2] + psq[sl * 4 + 3];
      float mu = sum * (1.0f / 1024.0f);
      float var = sq2 * (1.0f / 1024.0f) - mu * mu;
      float rstd = rsqrtf(var + 1e-5f);
#pragma unroll 4
      for (int i = 0; i < 32; ++i) {
        const int f = oct * 4 + i * 32;
        bh4 r4 = *(const bh4*)&sret[sl * 1040 + f];
        float4 g4 = *(const float4*)(ln_g + f);
        float4 b4 = *(const float4*)(ln_b + f);
        bh4 o;
        o.x = __float2bfloat16((b2f(r4.x) - mu) * rstd * g4.x + b4.x);
        o.y = __float2bfloat16((b2f(r4.y) - mu) * rstd * g4.y + b4.y);
        o.z = __float2bfloat16((b2f(r4.z) - mu) * rstd * g4.z + b4.z);
        o.w = __float2bfloat16((b2f(r4.w) - mu) * rstd * g4.w + b4.w);
        *(bh4*)(out + t * 1024 + f) = o;
      }
    }
    __syncthreads();
  }
}

// ---------------------------------------------------------------------------
extern "C" void kernel_launch(void* const* d_in, const int* in_sizes, int n_in,
                              void* d_out, int out_size, void* d_ws, size_t ws_size,
                              hipStream_t stream) {
  (void)in_sizes; (void)n_in; (void)out_size; (void)ws_size;
  const float* x   = (const float*)d_in[0];
  const float* Wk  = (const float*)d_in[1];
  const float* bk  = (const float*)d_in[2];
  const float* Wv  = (const float*)d_in[3];
  const float* bv  = (const float*)d_in[4];
  const float* Wq  = (const float*)d_in[5];
  const float* bq  = (const float*)d_in[6];
  const float* Wkp = (const float*)d_in[7];
  const float* bkp = (const float*)d_in[8];
  const float* Wqp = (const float*)d_in[9];
  const float* bqp = (const float*)d_in[10];
  const float* ps  = (const float*)d_in[11];
  const float* lng = (const float*)d_in[12];
  const float* lnb = (const float*)d_in[13];
  const float* Wo  = (const float*)d_in[14];
  const float* bo  = (const float*)d_in[15];
  float* out = (float*)d_out;

  char* ws = (char*)d_ws;
  bf16*  XB   = (bf16*)(ws);                  // [16384,1024] bf16 (x, later LN out)
  bf16*  PHS  = (bf16*)(ws + 33554432);       // [16384,3072] bf16: V | tanh_k | tanh_q
  bf16*  WBIG = (bf16*)(ws + 134217728);      // [3072,1024]: Wv | Wck | Wcq
  bf16*  WOB  = (bf16*)(ws + 140509184);      // [1024,1024]
  bf16*  WPS  = (bf16*)(ws + 142606336);      // [2048,1024]: Wkp ; Wqp (bf16)
  bf16*  WTS  = (bf16*)(ws + 146800640);      // [2048,1024]: Wk^T ; Wq^T (bf16)
  float* BBIG = (float*)(ws + 150994944);     // [3072]: bv | b'k | b'q

  // conversions / weight prep
  f2b_kernel<<<16384, 256, 0, stream>>>(x, XB, 16777216L);
  Ptrs4 p4;
  p4.s[0] = Wv;  p4.d[0] = WBIG;
  p4.s[1] = Wkp; p4.d[1] = WPS;
  p4.s[2] = Wqp; p4.d[2] = WPS + 1048576;
  p4.s[3] = Wo;  p4.d[3] = WOB;
  f2b4_kernel<<<4096, 256, 0, stream>>>(p4);
  f2bT_kernel<<<dim3(16, 16, 2), 256, 0, stream>>>(Wk, Wq, WTS, WTS + 1048576);
  copyvec_kernel<<<4, 256, 0, stream>>>(bv, BBIG);
  biasdot_kernel<<<2048, 256, 0, stream>>>(Wkp, bk, bkp, Wqp, bq, bqp, BBIG);

  // prep GEMM: [Wck;Wcq] = [Wkp;Wqp] @ [Wk^T;Wq^T]^T  (M=2048,N=1024,K=1024)
  gemm_bt<0, 1><<<128, 256, 0, stream>>>(WPS, WTS, nullptr, WBIG + 1048576,
                                         1024, 1024, 1024, nullptr);
  // main GEMM: PHS = [x@Wv^T+bv | tanh(x@Wck^T+b'k) | tanh(x@Wcq^T+b'q)]
  gemm256<1><<<768, 512, 131072, stream>>>(XB, WBIG, BBIG, PHS,
                                           1024, 3072, 1024, nullptr);
  // chunk scan + retrieve + LayerNorm -> XB (reused)
  scan_ln_kernel<<<256, 256, 0, stream>>>(PHS, ps, lng, lnb, XB);
  // final GEMM: out = x + LN @ Wo^T + bo
  gemm256<2><<<256, 512, 131072, stream>>>(XB, WOB, bo, out,
                                           1024, 1024, 1024, x);
}

// Round 7
// 410.185 us; speedup vs baseline: 1.5007x; 1.0155x over previous
//
#include <hip/hip_runtime.h>
#include <hip/hip_bf16.h>

typedef __hip_bfloat16 bf16;
typedef __attribute__((ext_vector_type(8))) short short8;
typedef __attribute__((ext_vector_type(4))) float f32x4;

struct alignas(8) bh4 { bf16 x, y, z, w; };

static __device__ __forceinline__ float b2f(bf16 h) { return __bfloat162float(h); }

// fast tanh: 1 - 2/(exp(2v)+1); saturates correctly via inf/0
static __device__ __forceinline__ float fast_tanh(float v) {
  float e = __expf(2.0f * v);
  return 1.0f - 2.0f * __builtin_amdgcn_rcpf(e + 1.0f);
}

// ---------------- fp32 -> bf16 conversion (x input) ------------------------
__global__ __launch_bounds__(256) void f2b_kernel(const float* __restrict__ s,
                                                  bf16* __restrict__ d, long n) {
  long i = ((long)blockIdx.x * 256 + threadIdx.x) * 4;
  if (i >= n) return;
  float4 v = *(const float4*)(s + i);
  bh4 o;
  o.x = __float2bfloat16(v.x); o.y = __float2bfloat16(v.y);
  o.z = __float2bfloat16(v.z); o.w = __float2bfloat16(v.w);
  *(bh4*)(d + i) = o;
}

// 4 x [1024,1024] fp32->bf16 in one launch
struct Ptrs4 { const float* s[4]; bf16* d[4]; };
__global__ __launch_bounds__(256) void f2b4_kernel(Ptrs4 p) {
  const int which = blockIdx.x >> 10;
  long i = ((long)(blockIdx.x & 1023) * 256 + threadIdx.x) * 4;
  float4 v = *(const float4*)(p.s[which] + i);
  bh4 o;
  o.x = __float2bfloat16(v.x); o.y = __float2bfloat16(v.y);
  o.z = __float2bfloat16(v.z); o.w = __float2bfloat16(v.w);
  *(bh4*)(p.d[which] + i) = o;
}

// ---------------- fp32 [1024,1024] -> transposed bf16 (2 mats) -------------
__global__ __launch_bounds__(256) void f2bT_kernel(const float* __restrict__ s0,
                                                   const float* __restrict__ s1,
                                                   bf16* __restrict__ d0,
                                                   bf16* __restrict__ d1) {
  const float* src = blockIdx.z ? s1 : s0;
  bf16* dst = blockIdx.z ? d1 : d0;
  __shared__ bf16 tile[64][68];
  const int t = threadIdx.x;
  const int tr = t >> 4;          // 0..15
  const int tc = (t & 15) * 4;    // 0..60
  const int r0 = blockIdx.y * 64, c0 = blockIdx.x * 64;
#pragma unroll
  for (int i = 0; i < 4; ++i) {
    float4 v = *(const float4*)(src + (long)(r0 + tr + i * 16) * 1024 + c0 + tc);
    tile[tr + i * 16][tc + 0] = __float2bfloat16(v.x);
    tile[tr + i * 16][tc + 1] = __float2bfloat16(v.y);
    tile[tr + i * 16][tc + 2] = __float2bfloat16(v.z);
    tile[tr + i * 16][tc + 3] = __float2bfloat16(v.w);
  }
  __syncthreads();
#pragma unroll
  for (int i = 0; i < 4; ++i) {
    const int c = tr + i * 16;
    bh4 o;
    o.x = tile[tc + 0][c]; o.y = tile[tc + 1][c];
    o.z = tile[tc + 2][c]; o.w = tile[tc + 3][c];
    *(bh4*)(dst + (long)(c0 + c) * 1024 + r0 + tc) = o;  // dst[C][R] = src[R][C]
  }
}

// ---------------- small copies / bias fold ---------------------------------
__global__ __launch_bounds__(256) void copyvec_kernel(const float* __restrict__ s,
                                                      float* __restrict__ d) {
  int i = blockIdx.x * 256 + threadIdx.x;
  d[i] = s[i];
}

// BBIG[1024+b] = dot(Wsel[e,:], bsel) + bpsel[e], b in [0,2048)
__global__ __launch_bounds__(256)
void biasdot_kernel(const float* __restrict__ Wkp, const float* __restrict__ bk,
                    const float* __restrict__ bkp, const float* __restrict__ Wqp,
                    const float* __restrict__ bq, const float* __restrict__ bqp,
                    float* __restrict__ BBIG) {
  const int b = blockIdx.x;
  const int half = b >> 10, e = b & 1023;
  const float* Wrow = (half ? Wqp : Wkp) + (long)e * 1024;
  const float* bsrc = half ? bq : bk;
  const int tid = threadIdx.x;
  float4 w = *(const float4*)(Wrow + tid * 4);
  float4 bb = *(const float4*)(bsrc + tid * 4);
  float p = w.x * bb.x + w.y * bb.y + w.z * bb.z + w.w * bb.w;
#pragma unroll
  for (int off = 32; off > 0; off >>= 1) p += __shfl_down(p, off, 64);
  __shared__ float rs[4];
  if ((tid & 63) == 0) rs[tid >> 6] = p;
  __syncthreads();
  if (tid == 0)
    BBIG[1024 + b] = rs[0] + rs[1] + rs[2] + rs[3] + (half ? bqp : bkp)[e];
}

// ---------------- bf16 GEMM (old 128^2 structure) — kept for prep only -----
#define TILE 128
#define BK 64

template <int MODE, int NXB>
__global__ __launch_bounds__(256)
void gemm_bt(const bf16* __restrict__ A, const bf16* __restrict__ W,
             const float* __restrict__ bias, void* __restrict__ Out,
             long lda, long ldc, int K,
             const float* __restrict__ resid) {
  __shared__ bf16 sA[TILE * BK];
  __shared__ bf16 sB[TILE * BK];

  const int id = blockIdx.x;
  const int xcd = id & 7;
  const int loc = id >> 3;
  const int bx = xcd * NXB + loc % NXB;
  const int by = loc / NXB;

  const int tid = threadIdx.x;
  const long row0 = (long)by * TILE;
  const long col0 = (long)bx * TILE;

  if (MODE == 0 && row0 >= 1024) W += 1024L * K;

  const int wave = tid >> 6;
  const int lane = tid & 63;
  const int wm = wave >> 1, wn = wave & 1;
  const int fr = lane & 15, quad = lane >> 4;
  const int sw = fr & 7;

  f32x4 acc[4][4];
#pragma unroll
  for (int i = 0; i < 4; ++i)
#pragma unroll
    for (int j = 0; j < 4; ++j) acc[i][j] = (f32x4)0.0f;

  const int urow = tid >> 3;
  const int gcolg = (tid & 7) ^ (urow & 7);
  const int ucol = gcolg * 8;

  for (int k0 = 0; k0 < K; k0 += BK) {
#pragma unroll
    for (int r = 0; r < 4; ++r) {
      const int rr = r * 32 + urow;
      const bf16* ga = A + (row0 + rr) * lda + k0 + ucol;
      const bf16* gb = W + (col0 + rr) * (long)K + k0 + ucol;
      bf16* la = &sA[(r * 256 + (wave << 6)) * 8];
      bf16* lb = &sB[(r * 256 + (wave << 6)) * 8];
      __builtin_amdgcn_global_load_lds((const __attribute__((address_space(1))) void*)ga,
                                       (__attribute__((address_space(3))) void*)la, 16, 0, 0);
      __builtin_amdgcn_global_load_lds((const __attribute__((address_space(1))) void*)gb,
                                       (__attribute__((address_space(3))) void*)lb, 16, 0, 0);
    }
    __syncthreads();

#pragma unroll
    for (int kk = 0; kk < BK; kk += 32) {
      const int kg = kk >> 3;
      short8 af[4], bfv[4];
#pragma unroll
      for (int i = 0; i < 4; ++i)
        af[i] = *(const short8*)&sA[(wm * 64 + i * 16 + fr) * BK + (((kg + quad) ^ sw) << 3)];
#pragma unroll
      for (int j = 0; j < 4; ++j)
        bfv[j] = *(const short8*)&sB[(wn * 64 + j * 16 + fr) * BK + (((kg + quad) ^ sw) << 3)];
#pragma unroll
      for (int i = 0; i < 4; ++i)
#pragma unroll
        for (int j = 0; j < 4; ++j)
          acc[i][j] = __builtin_amdgcn_mfma_f32_16x16x32_bf16(af[i], bfv[j], acc[i][j], 0, 0, 0);
    }
    __syncthreads();
  }

  const bool do_tanh = (MODE == 1) && (col0 >= 1024);
#pragma unroll
  for (int i = 0; i < 4; ++i) {
    const long rb = row0 + wm * 64 + i * 16 + quad * 4;
#pragma unroll
    for (int j = 0; j < 4; ++j) {
      const int col = (int)col0 + wn * 64 + j * 16 + fr;
      const float bc = (MODE == 0) ? 0.0f : bias[col];
#pragma unroll
      for (int reg = 0; reg < 4; ++reg) {
        const long r = rb + reg;
        float v = acc[i][j][reg] + bc;
        if (MODE == 0) {
          ((bf16*)Out)[r * ldc + col] = __float2bfloat16(v);
        } else if (MODE == 1) {
          if (do_tanh) v = fast_tanh(v);
          ((bf16*)Out)[r * ldc + col] = __float2bfloat16(v);
        } else {
          ((float*)Out)[r * ldc + col] = v + resid[r * ldc + col];
        }
      }
    }
  }
}

// ---------------- 256^2-tile 8-wave 8-phase GEMM (v4) ----------------------
// = round-4's EXACT wait/barrier skeleton (passed, 115 µs) + register+imm
// addressing only:
//  ph1: read A0-3 (8) + B0-1 (4) | stage A(u+1)h0 -> P^1 | Q00
//  ph2: read B2-3 (4)            | stage A(u+1)h1 -> P^1 | Q01
//  ph3: read A4-7 (8)            | stage B(u+2)h0 -> P   | Q10
//  ph4: (no reads)               | stage B(u+2)h1 -> P ; vmcnt(4) | Q11
// Each phase: reads+stage -> [lgkm(8) if 12 reads] -> barrier -> lgkm(0) ->
// sched_barrier(0) -> setprio(1) 16 MFMA setprio(0) -> barrier.
// Addressing: ds_reads via 4 loop-invariant base ptrs + compile-time imm
// offsets (max 47104 B < 64 KiB); staging via 8 named ptrs bumped +=64/tile.
#define LGKM0() asm volatile("s_waitcnt lgkmcnt(0)" ::: "memory")
#define LGKM8() asm volatile("s_waitcnt lgkmcnt(8)" ::: "memory")
#define VMC4()  asm volatile("s_waitcnt vmcnt(4)" ::: "memory")
#define VMC0()  asm volatile("s_waitcnt vmcnt(0)" ::: "memory")
#define SCHED0() __builtin_amdgcn_sched_barrier(0)
#define BARX()  do { asm volatile("" ::: "memory"); __builtin_amdgcn_s_barrier(); \
                     asm volatile("" ::: "memory"); } while (0)

#define GLD(GP, LP)                                                             \
  __builtin_amdgcn_global_load_lds((const __attribute__((address_space(1))) void*)(GP), \
                                   (__attribute__((address_space(3))) void*)(LP), 16, 0, 0)

// stage one 64-row slab: A slot (P,H,R) / B slot (P,H,R)
#define STG_A(P, H, R, GP) GLD(GP, sAB + (P) * 16384 + (H) * 8192 + (R) * 4096 + wave * 512)
#define STG_B(P, H, R, GP) GLD(GP, sAB + 32768 + (P) * 16384 + (H) * 8192 + (R) * 4096 + wave * 512)

// read A frags FI0..FI0+3 x 2 k-slices: base ptr + imm (P*32768 + f*2048 B)
#define RD_A(DST, P, FI0)                                                       \
  do {                                                                          \
    _Pragma("unroll")                                                           \
    for (int i2 = 0; i2 < 4; ++i2) {                                            \
      DST[i2][0] = *(const short8*)(dsA0 + (P) * 16384 + ((FI0) + i2) * 1024);  \
      DST[i2][1] = *(const short8*)(dsA1 + (P) * 16384 + ((FI0) + i2) * 1024);  \
    }                                                                           \
  } while (0)

#define RD_B(DST, P, FJ0)                                                       \
  do {                                                                          \
    _Pragma("unroll")                                                           \
    for (int j2 = 0; j2 < 2; ++j2) {                                            \
      DST[j2][0] = *(const short8*)(dsB0 + (P) * 16384 + ((FJ0) + j2) * 1024);  \
      DST[j2][1] = *(const short8*)(dsB1 + (P) * 16384 + ((FJ0) + j2) * 1024);  \
    }                                                                           \
  } while (0)

// one C-quadrant: 16 MFMA (4 M-frags x 2 N-frags x 2 k-slices)
#define QXN(AF, BF, MH, NH)                                                     \
  do {                                                                          \
    __builtin_amdgcn_s_setprio(1);                                              \
    _Pragma("unroll")                                                           \
    for (int kk = 0; kk < 2; ++kk)                                              \
      _Pragma("unroll")                                                         \
      for (int i2 = 0; i2 < 4; ++i2)                                            \
        _Pragma("unroll")                                                       \
        for (int j2 = 0; j2 < 2; ++j2)                                          \
          acc[(MH) * 4 + i2][(NH) * 2 + j2] = __builtin_amdgcn_mfma_f32_16x16x32_bf16( \
              AF[i2][kk], BF[j2][kk], acc[(MH) * 4 + i2][(NH) * 2 + j2], 0, 0, 0); \
    __builtin_amdgcn_s_setprio(0);                                              \
  } while (0)

// 4 phases of one K-tile u reading buf P (P literal 0/1)
#define TILEPH(u, P)                                                            \
  do {                                                                          \
    /* ph1 */                                                                   \
    RD_A(fa, P, 0);                                                             \
    RD_B(fbA, P, 0);                                                            \
    if ((u) + 1 < nt) { STG_A((P) ^ 1, 0, 0, gA00); STG_A((P) ^ 1, 0, 1, gA01); } \
    gA00 += 64; gA01 += 64;                                                     \
    LGKM8();                                                                    \
    BARX(); LGKM0(); SCHED0();                                                  \
    QXN(fa, fbA, 0, 0);                                                         \
    BARX();                                                                     \
    /* ph2 */                                                                   \
    RD_B(fbB, P, 2);                                                            \
    if ((u) + 1 < nt) { STG_A((P) ^ 1, 1, 0, gA10); STG_A((P) ^ 1, 1, 1, gA11); } \
    gA10 += 64; gA11 += 64;                                                     \
    BARX(); LGKM0(); SCHED0();                                                  \
    QXN(fa, fbB, 0, 1);                                                         \
    BARX();                                                                     \
    /* ph3 */                                                                   \
    RD_A(fa, P, 4);                                                             \
    if ((u) + 2 < nt) { STG_B(P, 0, 0, gB00); STG_B(P, 0, 1, gB01); }           \
    gB00 += 64; gB01 += 64;                                                     \
    BARX(); LGKM0(); SCHED0();                                                  \
    QXN(fa, fbA, 1, 0);                                                         \
    BARX();                                                                     \
    /* ph4 */                                                                   \
    if ((u) + 2 < nt) { STG_B(P, 1, 0, gB10); STG_B(P, 1, 1, gB11); VMC4(); }   \
    else { VMC0(); }                                                            \
    gB10 += 64; gB11 += 64;                                                     \
    BARX(); SCHED0();                                                           \
    QXN(fa, fbB, 1, 1);                                                         \
    BARX();                                                                     \
  } while (0)

template <int MODE>
__global__ __launch_bounds__(512, 2)
void gemm256(const bf16* __restrict__ A, const bf16* __restrict__ W,
             const float* __restrict__ bias, void* __restrict__ Out,
             long lda, long ldc, int K, const float* __restrict__ resid) {
  extern __shared__ __align__(16) char smem_raw[];
  bf16* sAB = (bf16*)smem_raw;   // [0,32768): A bufs; [32768,65536): B bufs (elems)

  const int id = blockIdx.x;
  const int xcd = id & 7;
  const int loc = id >> 3;
  const int by = xcd * 8 + (loc & 7);   // M=16384 -> 64 row tiles, 8 per XCD
  const int bx = loc >> 3;
  const long row0 = (long)by * 256;
  const long col0 = (long)bx * 256;
  const long ldb = (long)K;

  const int tid = threadIdx.x;
  const int wave = tid >> 6, lane = tid & 63;
  const int wm = wave >> 2, wn = wave & 3;
  const int fr = lane & 15, quad = lane >> 4;
  const int sw = fr & 7;
  const int srow = tid >> 3;                       // 0..63 (staging row)
  const int sgcol = ((tid & 7) ^ (srow & 7)) << 3; // pre-swizzled global col

  const int nt = K >> 6;   // 16 (even)

  // loop-invariant ds_read base pointers (all frag/buf selects are imm offs)
  const bf16* dsA0 = sAB + (wm * 128 + fr) * 64 + ((quad ^ sw) << 3);
  const bf16* dsA1 = sAB + (wm * 128 + fr) * 64 + (((4 + quad) ^ sw) << 3);
  const bf16* dsB0 = sAB + 32768 + (wn * 64 + fr) * 64 + ((quad ^ sw) << 3);
  const bf16* dsB1 = sAB + 32768 + (wn * 64 + fr) * 64 + (((4 + quad) ^ sw) << 3);

  // named stage pointers (slot = matrix/half/row-slab), bumped +=64 per tile
  const bf16* gA00 = A + (row0 + 0 + srow) * lda + sgcol;
  const bf16* gA01 = A + (row0 + 64 + srow) * lda + sgcol;
  const bf16* gA10 = A + (row0 + 128 + srow) * lda + sgcol;
  const bf16* gA11 = A + (row0 + 192 + srow) * lda + sgcol;
  const bf16* gB00 = W + (col0 + 0 + srow) * ldb + sgcol;
  const bf16* gB01 = W + (col0 + 64 + srow) * ldb + sgcol;
  const bf16* gB10 = W + (col0 + 128 + srow) * ldb + sgcol;
  const bf16* gB11 = W + (col0 + 192 + srow) * ldb + sgcol;

  f32x4 acc[8][4];
#pragma unroll
  for (int i = 0; i < 8; ++i)
#pragma unroll
    for (int j = 0; j < 4; ++j) acc[i][j] = (f32x4)0.0f;

  // phase-local fragments: fa holds A0-3 (ph1-2) then A4-7 (ph3-4)
  short8 fa[4][2], fbA[2][2], fbB[2][2];

  // prologue: tile0 (A+B) -> buf0; B(1) -> buf1; retire tile0, keep B(1) flying
  STG_A(0, 0, 0, gA00); STG_A(0, 0, 1, gA01);
  STG_A(0, 1, 0, gA10); STG_A(0, 1, 1, gA11);
  gA00 += 64; gA01 += 64; gA10 += 64; gA11 += 64;          // -> tile1
  STG_B(0, 0, 0, gB00); STG_B(0, 0, 1, gB01);
  STG_B(0, 1, 0, gB10); STG_B(0, 1, 1, gB11);
  gB00 += 64; gB01 += 64; gB10 += 64; gB11 += 64;          // -> tile1
  STG_B(1, 0, 0, gB00); STG_B(1, 0, 1, gB01);
  STG_B(1, 1, 0, gB10); STG_B(1, 1, 1, gB11);
  gB00 += 64; gB01 += 64; gB10 += 64; gB11 += 64;          // -> tile2
  VMC4();   // retire tile0's 8 loads; B(1)'s 4 stay in flight
  BARX();

  for (int it = 0; it < nt; it += 2) {
    TILEPH(it, 0);
    TILEPH(it + 1, 1);
  }

  const bool do_tanh = (MODE == 1) && (col0 >= 1024);
  // C/D layout: col = lane&15, row = quad*4 + reg (m89/m91 verified)
#pragma unroll
  for (int mi = 0; mi < 8; ++mi) {
    const long rbase = row0 + wm * 128 + mi * 16 + quad * 4;
#pragma unroll
    for (int nj = 0; nj < 4; ++nj) {
      const int col = (int)col0 + wn * 64 + nj * 16 + fr;
      const float bc = bias[col];
#pragma unroll
      for (int reg = 0; reg < 4; ++reg) {
        const long r = rbase + reg;
        float v = acc[mi][nj][reg] + bc;
        if (MODE == 1) {
          if (do_tanh) v = fast_tanh(v);
          ((bf16*)Out)[r * ldc + col] = __float2bfloat16(v);
        } else {
          ((float*)Out)[r * ldc + col] = v + resid[r * ldc + col];
        }
      }
    }
  }
}

// ---------------- chunk-64 cumsum + retrieve + LayerNorm -------------------
__global__ __launch_bounds__(256)
void scan_ln_kernel(const bf16* __restrict__ PHS,   // [16384,3072]: V | tanh_k | tanh_q
                    const float* __restrict__ phase_scale,
                    const float* __restrict__ ln_g,
                    const float* __restrict__ ln_b,
                    bf16* __restrict__ out) {
  __shared__ bf16 sret[32 * 1040];   // stride 1040: 2-way max in phase 2
  __shared__ float psum[32 * 4], psq[32 * 4];

  const int tid = threadIdx.x;
  const long t0 = (long)blockIdx.x * 64;
  const int d = tid * 4;
  const int wid = tid >> 6, lane = tid & 63;

  const float inv2pi = 0.15915494309189535f;
  float4 ps = *(const float4*)(phase_scale + d);
  float psr[4] = {ps.x * inv2pi, ps.y * inv2pi, ps.z * inv2pi, ps.w * inv2pi};

  float ar[4] = {0.f, 0.f, 0.f, 0.f}, ai[4] = {0.f, 0.f, 0.f, 0.f};

  const int p2s = tid >> 3;          // phase-2 token slot 0..31
  const int oct = tid & 7;           // phase-2 feature octant

  for (int h = 0; h < 2; ++h) {
    for (int sl = 0; sl < 32; ++sl) {
      const long t = t0 + h * 32 + sl;
      const bf16* row = PHS + t * 3072;
      bh4 v4  = *(const bh4*)(row + d);
      bh4 tk4 = *(const bh4*)(row + 1024 + d);
      bh4 tq4 = *(const bh4*)(row + 2048 + d);
      float vv[4] = {b2f(v4.x), b2f(v4.y), b2f(v4.z), b2f(v4.w)};
      float tk[4] = {b2f(tk4.x), b2f(tk4.y), b2f(tk4.z), b2f(tk4.w)};
      float tq[4] = {b2f(tq4.x), b2f(tq4.y), b2f(tq4.z), b2f(tq4.w)};
      float ret[4];
      float lsum = 0.f, lsq = 0.f;
#pragma unroll
      for (int j = 0; j < 4; ++j) {
        float rk = tk[j] * psr[j];   // revolutions
        float rq = tq[j] * psr[j];
        float ck = __builtin_amdgcn_cosf(rk);
        float sk = __builtin_amdgcn_sinf(rk);
        float cq = __builtin_amdgcn_cosf(rq);
        float sq = __builtin_amdgcn_sinf(rq);
        ar[j] += vv[j] * ck;
        ai[j] += vv[j] * sk;
        ret[j] = (ar[j] * cq + ai[j] * sq) * 0.03125f;  // / sqrt(1024)
        lsum += ret[j];
        lsq += ret[j] * ret[j];
      }
      bh4 o;
      o.x = __float2bfloat16(ret[0]); o.y = __float2bfloat16(ret[1]);
      o.z = __float2bfloat16(ret[2]); o.w = __float2bfloat16(ret[3]);
      *(bh4*)&sret[sl * 1040 + d] = o;
#pragma unroll
      for (int off = 32; off > 0; off >>= 1) {
        lsum += __shfl_down(lsum, off, 64);
        lsq  += __shfl_down(lsq, off, 64);
      }
      if (lane == 0) { psum[sl * 4 + wid] = lsum; psq[sl * 4 + wid] = lsq; }
    }
    __syncthreads();
    {
      const int sl = p2s;
      const long t = t0 + h * 32 + sl;
      float sum = psum[sl * 4] + psum[sl * 4 + 1] + psum[sl * 4 + 2] + psum[sl * 4 + 3];
      float sq2 = psq[sl * 4] + psq[sl * 4 + 1] + psq[sl * 4 + 2] + psq[sl * 4 + 3];
      float mu = sum * (1.0f / 1024.0f);
      float var = sq2 * (1.0f / 1024.0f) - mu * mu;
      float rstd = rsqrtf(var + 1e-5f);
#pragma unroll 4
      for (int i = 0; i < 32; ++i) {
        const int f = oct * 4 + i * 32;
        bh4 r4 = *(const bh4*)&sret[sl * 1040 + f];
        float4 g4 = *(const float4*)(ln_g + f);
        float4 b4 = *(const float4*)(ln_b + f);
        bh4 o;
        o.x = __float2bfloat16((b2f(r4.x) - mu) * rstd * g4.x + b4.x);
        o.y = __float2bfloat16((b2f(r4.y) - mu) * rstd * g4.y + b4.y);
        o.z = __float2bfloat16((b2f(r4.z) - mu) * rstd * g4.z + b4.z);
        o.w = __float2bfloat16((b2f(r4.w) - mu) * rstd * g4.w + b4.w);
        *(bh4*)(out + t * 1024 + f) = o;
      }
    }
    __syncthreads();
  }
}

// ---------------------------------------------------------------------------
extern "C" void kernel_launch(void* const* d_in, const int* in_sizes, int n_in,
                              void* d_out, int out_size, void* d_ws, size_t ws_size,
                              hipStream_t stream) {
  (void)in_sizes; (void)n_in; (void)out_size; (void)ws_size;
  const float* x   = (const float*)d_in[0];
  const float* Wk  = (const float*)d_in[1];
  const float* bk  = (const float*)d_in[2];
  const float* Wv  = (const float*)d_in[3];
  const float* bv  = (const float*)d_in[4];
  const float* Wq  = (const float*)d_in[5];
  const float* bq  = (const float*)d_in[6];
  const float* Wkp = (const float*)d_in[7];
  const float* bkp = (const float*)d_in[8];
  const float* Wqp = (const float*)d_in[9];
  const float* bqp = (const float*)d_in[10];
  const float* ps  = (const float*)d_in[11];
  const float* lng = (const float*)d_in[12];
  const float* lnb = (const float*)d_in[13];
  const float* Wo  = (const float*)d_in[14];
  const float* bo  = (const float*)d_in[15];
  float* out = (float*)d_out;

  char* ws = (char*)d_ws;
  bf16*  XB   = (bf16*)(ws);                  // [16384,1024] bf16 (x, later LN out)
  bf16*  PHS  = (bf16*)(ws + 33554432);       // [16384,3072] bf16: V | tanh_k | tanh_q
  bf16*  WBIG = (bf16*)(ws + 134217728);      // [3072,1024]: Wv | Wck | Wcq
  bf16*  WOB  = (bf16*)(ws + 140509184);      // [1024,1024]
  bf16*  WPS  = (bf16*)(ws + 142606336);      // [2048,1024]: Wkp ; Wqp (bf16)
  bf16*  WTS  = (bf16*)(ws + 146800640);      // [2048,1024]: Wk^T ; Wq^T (bf16)
  float* BBIG = (float*)(ws + 150994944);     // [3072]: bv | b'k | b'q

  // conversions / weight prep
  f2b_kernel<<<16384, 256, 0, stream>>>(x, XB, 16777216L);
  Ptrs4 p4;
  p4.s[0] = Wv;  p4.d[0] = WBIG;
  p4.s[1] = Wkp; p4.d[1] = WPS;
  p4.s[2] = Wqp; p4.d[2] = WPS + 1048576;
  p4.s[3] = Wo;  p4.d[3] = WOB;
  f2b4_kernel<<<4096, 256, 0, stream>>>(p4);
  f2bT_kernel<<<dim3(16, 16, 2), 256, 0, stream>>>(Wk, Wq, WTS, WTS + 1048576);
  copyvec_kernel<<<4, 256, 0, stream>>>(bv, BBIG);
  biasdot_kernel<<<2048, 256, 0, stream>>>(Wkp, bk, bkp, Wqp, bq, bqp, BBIG);

  // prep GEMM: [Wck;Wcq] = [Wkp;Wqp] @ [Wk^T;Wq^T]^T  (M=2048,N=1024,K=1024)
  gemm_bt<0, 1><<<128, 256, 0, stream>>>(WPS, WTS, nullptr, WBIG + 1048576,
                                         1024, 1024, 1024, nullptr);
  // main GEMM: PHS = [x@Wv^T+bv | tanh(x@Wck^T+b'k) | tanh(x@Wcq^T+b'q)]
  gemm256<1><<<768, 512, 131072, stream>>>(XB, WBIG, BBIG, PHS,
                                           1024, 3072, 1024, nullptr);
  // chunk scan + retrieve + LayerNorm -> XB (reused)
  scan_ln_kernel<<<256, 256, 0, stream>>>(PHS, ps, lng, lnb, XB);
  // final GEMM: out = x + LN @ Wo^T + bo
  gemm256<2><<<256, 512, 131072, stream>>>(XB, WOB, bo, out,
                                           1024, 1024, 1024, x);
}